// Round 6
// baseline (852.874 us; speedup 1.0000x reference)
//
#include <hip/hip_runtime.h>
#include <math.h>

#define TBL   (1u << 19)
#define TMASK (TBL - 1u)
#define PRIME1 2654435761u
#define PRIME2 805459861u

typedef float v2f __attribute__((ext_vector_type(2)));
typedef float v4f __attribute__((ext_vector_type(4)));

struct LevelParams {
    float    scale[16];
    unsigned res[16];
    unsigned dense[16];
};

__device__ __forceinline__ void corner_indices(
    float x, float y, float z, float s, unsigned res, unsigned dense,
    unsigned idx[8], float* wx, float* wy, float* wz)
{
    float px = __fadd_rn(__fmul_rn(x, s), 0.5f);
    float py = __fadd_rn(__fmul_rn(y, s), 0.5f);
    float pz = __fadd_rn(__fmul_rn(z, s), 0.5f);
    float fx = floorf(px), fy = floorf(py), fz = floorf(pz);
    *wx = px - fx; *wy = py - fy; *wz = pz - fz;
    unsigned gx = (unsigned)fx, gy = (unsigned)fy, gz = (unsigned)fz;

    if (dense) {
        const unsigned rm1 = res - 1u;
        unsigned cx0 = min(gx, rm1),   cx1 = min(gx + 1u, rm1);
        unsigned cy0 = min(gy, rm1),   cy1 = min(gy + 1u, rm1);
        unsigned cz0 = min(gz, rm1),   cz1 = min(gz + 1u, rm1);
        unsigned y0 = cy0 * res,       y1 = cy1 * res;
        unsigned z0 = cz0 * res * res, z1 = cz1 * res * res;
        idx[0] = cx0 + y0 + z0;  idx[1] = cx0 + y0 + z1;
        idx[2] = cx0 + y1 + z0;  idx[3] = cx0 + y1 + z1;
        idx[4] = cx1 + y0 + z0;  idx[5] = cx1 + y0 + z1;
        idx[6] = cx1 + y1 + z0;  idx[7] = cx1 + y1 + z1;
    } else {
        unsigned hx0 = gx,          hx1 = gx + 1u;
        unsigned hy0 = gy * PRIME1, hy1 = hy0 + PRIME1;
        unsigned hz0 = gz * PRIME2, hz1 = hz0 + PRIME2;
        idx[0] = (hx0 ^ hy0 ^ hz0) & TMASK;
        idx[1] = (hx0 ^ hy0 ^ hz1) & TMASK;
        idx[2] = (hx0 ^ hy1 ^ hz0) & TMASK;
        idx[3] = (hx0 ^ hy1 ^ hz1) & TMASK;
        idx[4] = (hx1 ^ hy0 ^ hz0) & TMASK;
        idx[5] = (hx1 ^ hy0 ^ hz1) & TMASK;
        idx[6] = (hx1 ^ hy1 ^ hz0) & TMASK;
        idx[7] = (hx1 ^ hy1 ^ hz1) & TMASK;
    }
}

// Paired 16B gather: each corner loads the aligned 16B entry-pair containing
// it (tab4[idx>>1]) and selects by idx&1 (proven: R1 pass_a 544->477us; R5
// established per-level time is invariant to cache residency -> L2-request-
// rate bound, so these 6 distinct lines/pt are the irreducible clock).
__device__ __forceinline__ v2f interp_level(
    const v4f* __restrict__ tab4,
    float x, float y, float z, float s, unsigned res, unsigned dense)
{
    unsigned idx[8];
    float wx, wy, wz;
    corner_indices(x, y, z, s, res, dense, idx, &wx, &wy, &wz);

    float wx0 = 1.f - wx, wy0 = 1.f - wy, wz0 = 1.f - wz;
    float wyz00 = wy0 * wz0, wyz01 = wy0 * wz;
    float wyz10 = wy  * wz0, wyz11 = wy  * wz;
    float cw0[4] = { wx0 * wyz00, wx0 * wyz01, wx0 * wyz10, wx0 * wyz11 };
    float cw1[4] = { wx  * wyz00, wx  * wyz01, wx  * wyz10, wx  * wyz11 };

    float f0 = 0.f, f1 = 0.f;
    #pragma unroll
    for (int k = 0; k < 4; ++k) {
        unsigned i0 = idx[k], i1 = idx[k + 4];
        v4f q0 = tab4[i0 >> 1];
        v4f q1 = tab4[i1 >> 1];
        float a0 = (i0 & 1u) ? q0.z : q0.x;
        float b0 = (i0 & 1u) ? q0.w : q0.y;
        float a1 = (i1 & 1u) ? q1.z : q1.x;
        float b1 = (i1 & 1u) ? q1.w : q1.y;
        f0 = fmaf(cw0[k], a0, f0);
        f1 = fmaf(cw0[k], b0, f1);
        f0 = fmaf(cw1[k], a1, f0);
        f1 = fmaf(cw1[k], b1, f1);
    }
    v2f r; r.x = f0; r.y = f1;
    return r;
}

// ---------- Fused: all 16 levels -> LDS transpose -> NT v4f out ----------
// No ws round-trip (saves 256MB + ~190us serialized pass_b). Per-level LDS
// deposit (no register v[16] -> low VGPR), ONE barrier total (R4 showed
// per-level barriers cost ~7us/level). 33.8KB LDS -> 4 blocks/CU = 16
// waves; per R5's null result the gather rate is L2-request-bound and
// should be occupancy-insensitive at >=16 waves -- this run is the test.
__global__ __launch_bounds__(256, 4) void fused_enc(
    const float* __restrict__ coords,
    const float* __restrict__ table,
    float* __restrict__ out,
    LevelParams lp, unsigned n)
{
    __shared__ float lds[256 * 33];
    const unsigned t  = threadIdx.x;
    const unsigned p0 = blockIdx.x * 256u;
    const unsigned p  = p0 + t;

    float x = 0.f, y = 0.f, z = 0.f;
    if (p < n) {
        x = coords[3ull * p + 0];
        y = coords[3ull * p + 1];
        z = coords[3ull * p + 2];
    }

    #pragma unroll 2
    for (int l = 0; l < 16; ++l) {
        const v4f* __restrict__ tab4 =
            (const v4f*)(table + (size_t)l * (2u * TBL));
        v2f r = interp_level(tab4, x, y, z, lp.scale[l], lp.res[l],
                             lp.dense[l]);
        lds[t * 33u + 2u * l]      = r.x;   // stride 33: 2-way conflict (free)
        lds[t * 33u + 2u * l + 1u] = r.y;
    }
    __syncthreads();

    // coalesced NT v4f stores: 8 per thread, 1KB per wave-instruction.
    // LDS read pattern: lanes 0..7 read pt fixed, c=0,4,..,28 -> banks
    // 0..31 exactly once per 8-lane group; +33 per group keeps it distinct.
    v4f* __restrict__ out4 = (v4f*)out;
    const size_t base4  = (size_t)p0 * 8u;
    const size_t total4 = (size_t)n * 8u;
    #pragma unroll
    for (int i = 0; i < 8; ++i) {
        unsigned j = (unsigned)i * 256u + t;     // 0..2047 v4f in tile
        size_t o = base4 + j;
        if (o < total4) {
            unsigned pt = j >> 3, c = (j & 7u) * 4u;
            v4f q;
            q.x = lds[pt * 33u + c + 0u];
            q.y = lds[pt * 33u + c + 1u];
            q.z = lds[pt * 33u + c + 2u];
            q.w = lds[pt * 33u + c + 3u];
            __builtin_nontemporal_store(q, out4 + o);
        }
    }
}

extern "C" void kernel_launch(void* const* d_in, const int* in_sizes, int n_in,
                              void* d_out, int out_size, void* d_ws, size_t ws_size,
                              hipStream_t stream) {
    (void)n_in; (void)out_size; (void)d_ws; (void)ws_size;
    const float* coords = (const float*)d_in[0];
    const float* table  = (const float*)d_in[1];
    float* out = (float*)d_out;

    LevelParams lp;
    for (int l = 0; l < 16; ++l) {
        double scale = 16.0 * pow(1.4472692012786865, (double)l) - 1.0;
        int res = (int)ceil(scale) + 1;
        lp.scale[l] = (float)scale;
        lp.res[l]   = (unsigned)res;
        long long r3 = (long long)res * res * res;
        lp.dense[l] = (r3 <= (long long)TBL) ? 1u : 0u;
    }

    unsigned n = (unsigned)(in_sizes[0] / 3);
    unsigned chunks = (n + 255u) / 256u;

    hipLaunchKernelGGL(fused_enc, dim3(chunks), dim3(256), 0, stream,
                       coords, table, out, lp, n);
}